// Round 14
// baseline (400.274 us; speedup 1.0000x reference)
//
#include <hip/hip_runtime.h>

typedef unsigned short us;
typedef unsigned int uns;
typedef __attribute__((ext_vector_type(8))) short short8;
typedef __attribute__((ext_vector_type(4))) float floatx4;

__device__ __forceinline__ us f2b(float f) {
    union { float f; unsigned u; } x; x.f = f;
    unsigned r = x.u + 0x7fffu + ((x.u >> 16) & 1u);
    return (us)(r >> 16);
}
__device__ __forceinline__ float b2f(us u) {
    union { unsigned u; float f; } x; x.u = ((unsigned)u) << 16; return x.f;
}
__device__ __forceinline__ uns fbits(float f) {
    union { float f; unsigned u; } x; x.f = f; return x.u;
}
__device__ __forceinline__ uns pk2(float hi, float lo) {
    return __builtin_amdgcn_perm(fbits(hi) + 0x8000u, fbits(lo) + 0x8000u, 0x07060302u);
}
__device__ __forceinline__ uns pk2t(float hi, float lo) {
    return __builtin_amdgcn_perm(fbits(hi), fbits(lo), 0x07060302u);
}
__device__ __forceinline__ float fexp2(float x) {
#if __has_builtin(__builtin_amdgcn_exp2f)
    return __builtin_amdgcn_exp2f(x);
#else
    float r; asm volatile("v_exp_f32 %0, %1\n\ts_nop 1" : "=v"(r) : "v"(x));
    return r;
#endif
}

#define C_DIM 256
#define N_DIM 4096
#define CN (C_DIM * N_DIM)
#define CSC (0.17677669529663687f * 1.4426950408889634f)   // 1/sqrt(32)*log2e
#define NB 512   // grid: 2 blocks/CU guaranteed co-resident via launch_bounds(256,2)

// grid barrier: monotone counter; release/acquire via agent-scope fences
// (threadfence -> L2 writeback/inv: required for cross-XCD phase data).
__device__ __forceinline__ void gbar(uns* cnt, uns target) {
    __syncthreads();
    if (threadIdx.x == 0) {
        __threadfence();
        atomicAdd(cnt, 1u);
        while (__hip_atomic_load(cnt, __ATOMIC_RELAXED, __HIP_MEMORY_SCOPE_AGENT) < target)
            __builtin_amdgcn_s_sleep(8);
        __threadfence();
    }
    __syncthreads();
}

__global__ __launch_bounds__(256, 2) void k_mega(
        const float* __restrict__ x, const float* __restrict__ gamma,
        const float* __restrict__ beta,
        const float* __restrict__ Wq, const float* __restrict__ Wk,
        const float* __restrict__ Wv, const float* __restrict__ Wo,
        const float* __restrict__ pbq, const float* __restrict__ pbk,
        const float* __restrict__ pbv, const float* __restrict__ pbo,
        float* __restrict__ part, us* __restrict__ Wb, float* __restrict__ bst,
        us* __restrict__ XT, us* __restrict__ QT, us* __restrict__ num1,
        float* __restrict__ den, us* __restrict__ Vb, us* __restrict__ KTg,
        float* __restrict__ Out, uns* cnt) {
    __shared__ float r1[256], r2[256];
    __shared__ float scs[32], offs[32], mv[2];
    __shared__ us Pb[4][2][1024];
    const int b = blockIdx.x, t = threadIdx.x;
    const int l = t & 63, w = t >> 6, l15 = l & 15, quad = l >> 4;
    us* num0 = XT;   // XT region reused as attention numerator after phase 2

    // ================= phase 0: weight prep + GN stat partials =================
    {
#pragma unroll
        for (int r = 0; r < 2; ++r) {
            int e = b * 512 + r * 256 + t;        // [0, 262144)
            int sel = e >> 16, idx = e & 65535;
            const float* Ws = sel == 0 ? Wq : sel == 1 ? Wk : sel == 2 ? Wv : Wo;
            Wb[e] = f2b(Ws[idx] * (sel == 0 ? CSC : 1.f));
        }
        if (b < 4) {
            float v = b == 0 ? pbq[t] * CSC : b == 1 ? pbk[t] : b == 2 ? pbv[t] : pbo[t];
            bst[b * 256 + t] = v;
        }
#pragma unroll
        for (int r = 0; r < 2; ++r) {
            int j = b * 2 + r;                    // 1024 stat jobs
            int bg = j >> 6, sl = j & 63;
            const float* base = x + (size_t)bg * 131072 + (size_t)sl * 2048 + t * 8;
            float4 a = *(const float4*)base;
            float4 bb = *(const float4*)(base + 4);
            float s  = a.x + a.y + a.z + a.w + bb.x + bb.y + bb.z + bb.w;
            float ss = a.x*a.x + a.y*a.y + a.z*a.z + a.w*a.w
                     + bb.x*bb.x + bb.y*bb.y + bb.z*bb.z + bb.w*bb.w;
            __syncthreads();                      // protect r1/r2 reuse
            r1[t] = s; r2[t] = ss;
            __syncthreads();
            for (int off = 128; off > 0; off >>= 1) {
                if (t < off) { r1[t] += r1[t + off]; r2[t] += r2[t + off]; }
                __syncthreads();
            }
            if (t == 0) { part[j * 2] = r1[0]; part[j * 2 + 1] = r2[0]; }
        }
    }
    gbar(cnt, NB);

    // ================= phase 1: normalize -> XT[z][n][c] =================
    {
#pragma unroll
        for (int r = 0; r < 2; ++r) {
            int j = b * 2 + r;                    // 1024 jobs: 64 n x one group
            int z = j >> 9, g = (j >> 6) & 7, nt = j & 63;
            int bg = z * 8 + g;
            __syncthreads();
            if (t < 64) {
                float s  = part[(bg * 64 + t) * 2];
                float ss = part[(bg * 64 + t) * 2 + 1];
#pragma unroll
                for (int off = 1; off < 64; off <<= 1) {
                    s  += __shfl_xor(s, off, 64);
                    ss += __shfl_xor(ss, off, 64);
                }
                if (t == 0) {
                    const float inv = 1.f / 131072.f;
                    float mean = s * inv;
                    float var  = ss * inv - mean * mean;
                    mv[0] = mean; mv[1] = rsqrtf(var + 1e-5f);
                }
            }
            __syncthreads();
            if (t < 32) {
                float sc = mv[1] * gamma[g * 32 + t];
                scs[t]  = sc;
                offs[t] = beta[g * 32 + t] - mv[0] * sc;
            }
            __syncthreads();
            int n = nt * 64 + (t & 63), c0 = (t >> 6) * 8;
            const float* xp = x + ((size_t)z * 256 + g * 32 + c0) * N_DIM + n;
            us* op = XT + ((size_t)z * N_DIM + n) * 256 + g * 32 + c0;
            short8 o;
#pragma unroll
            for (int i = 0; i < 8; ++i) {
                float v = xp[(size_t)i * N_DIM];
                o[i] = (short)f2b(v * scs[c0 + i] + offs[c0 + i]);
            }
            *(short8*)op = o;
        }
    }
    gbar(cnt, 2 * NB);

    // ================= phase 2: QKV GEMM (barrier-free body) =================
    {
#pragma unroll
        for (int r = 0; r < 3; ++r) {
            int j = b + r * NB;                   // 1536 jobs
            int z = j >= 768, rem = j - z * 768;
            int my = rem >> 6, nx = rem & 63;
            int n0 = nx * 64, m0 = my * 64;
            const int wm = m0 + (w >> 1) * 32, wn = n0 + (w & 1) * 32;
            const us* Ap = Wb + (size_t)(wm + l15) * 256 + quad * 8;
            const us* Bp = XT + ((size_t)z * N_DIM + wn + l15) * 256 + quad * 8;
            floatx4 acc[2][2] = {};
#pragma unroll
            for (int k0 = 0; k0 < 256; k0 += 32) {
                short8 a0 = *(const short8*)(Ap + k0);
                short8 a1 = *(const short8*)(Ap + k0 + 16 * 256);
                short8 b0 = *(const short8*)(Bp + k0);
                short8 b1 = *(const short8*)(Bp + k0 + 16 * 256);
                acc[0][0] = __builtin_amdgcn_mfma_f32_16x16x32_bf16(a0, b0, acc[0][0], 0, 0, 0);
                acc[0][1] = __builtin_amdgcn_mfma_f32_16x16x32_bf16(a0, b1, acc[0][1], 0, 0, 0);
                acc[1][0] = __builtin_amdgcn_mfma_f32_16x16x32_bf16(a1, b0, acc[1][0], 0, 0, 0);
                acc[1][1] = __builtin_amdgcn_mfma_f32_16x16x32_bf16(a1, b1, acc[1][1], 0, 0, 0);
            }
            if (my < 8) {   // Q or K: packed-transposed [bh][n][32]
                us* Dst = (my < 4) ? QT : KTg;
                const int h = (wm >> 5) & 7, bh = z * 8 + h;
#pragma unroll
                for (int mt = 0; mt < 2; ++mt) {
                    const int d0 = mt * 16 + quad * 4;
                    float b0v = bst[wm + mt * 16 + quad * 4 + 0];
                    float b1v = bst[wm + mt * 16 + quad * 4 + 1];
                    float b2v = bst[wm + mt * 16 + quad * 4 + 2];
                    float b3v = bst[wm + mt * 16 + quad * 4 + 3];
#pragma unroll
                    for (int nt = 0; nt < 2; ++nt) {
                        int col = wn + nt * 16 + l15;
                        uint2 pw;
                        pw.x = pk2(acc[mt][nt][1] + b1v, acc[mt][nt][0] + b0v);
                        pw.y = pk2(acc[mt][nt][3] + b3v, acc[mt][nt][2] + b2v);
                        *(uint2*)(Dst + ((size_t)bh * N_DIM + col) * 32 + d0) = pw;
                    }
                }
            } else {        // V rows natural [c][n]
#pragma unroll
                for (int mt = 0; mt < 2; ++mt)
#pragma unroll
                    for (int nt = 0; nt < 2; ++nt)
#pragma unroll
                        for (int rr = 0; rr < 4; ++rr) {
                            int row = wm + mt * 16 + quad * 4 + rr;
                            int col = wn + nt * 16 + l15;
                            Vb[((size_t)z * 256 + (row - 512)) * N_DIM + col] =
                                f2b(acc[mt][nt][rr] + bst[row]);
                        }
            }
        }
    }
    gbar(cnt, 3 * NB);

    // ================= phase 3: attention (r13 split-K body, 2 jobs) =========
    {
        short8 ones;
#pragma unroll
        for (int jj = 0; jj < 8; ++jj) ones[jj] = (short)0x3F80;
        const int sb = ((quad >> 1) * 16 + l15) * 8 + (quad & 1) * 4;
#pragma unroll
        for (int r = 0; r < 2; ++r) {
            int j = b + r * NB;                   // 1024 jobs
            int qx = j & 31, bh = (j >> 5) & 15, ks = j >> 9;
            int z = bh >> 3, h = bh & 7;
            const us* KTp = KTg + (size_t)bh * N_DIM * 32;
            const us* Vp  = Vb  + ((size_t)z * 256 + h * 32) * N_DIM;
            const int q0 = qx * 128 + w * 32;
            const int kbase0 = ks * 2048;
            short8 bq[2];
#pragma unroll
            for (int tl = 0; tl < 2; ++tl)
                bq[tl] = *(const short8*)(QT + ((size_t)bh * N_DIM + q0 + tl * 16 + l15) * 32 + quad * 8);
            floatx4 o1[2] = {}, o2[2] = {}, o3[2] = {};
            const us* kb  = KTp + l15 * 32 + quad * 8;
            const us* vb1 = Vp + (size_t)l15 * N_DIM + quad * 8;
            const us* vb2 = Vp + (size_t)(16 + l15) * N_DIM + quad * 8;
            short8 ak1 = *(const short8*)(kb + (size_t)kbase0 * 32);
            short8 ak2 = *(const short8*)(kb + (size_t)kbase0 * 32 + 512);
            short8 ak3 = *(const short8*)(kb + (size_t)kbase0 * 32 + 1024);
            short8 ak4 = *(const short8*)(kb + (size_t)kbase0 * 32 + 1536);

            for (int m0 = kbase0; m0 < kbase0 + 2048; m0 += 64) {
                short8 a11 = *(const short8*)(vb1 + m0);
                short8 a12 = *(const short8*)(vb1 + m0 + 32);
                short8 a21 = *(const short8*)(vb2 + m0);
                short8 a22 = *(const short8*)(vb2 + m0 + 32);
                const size_t mn = (size_t)((m0 + 64) & (N_DIM - 1)) * 32;
                short8 nk1 = *(const short8*)(kb + mn);
                short8 nk2 = *(const short8*)(kb + mn + 512);
                short8 nk3 = *(const short8*)(kb + mn + 1024);
                short8 nk4 = *(const short8*)(kb + mn + 1536);

                asm volatile("" ::: "memory");

#pragma unroll
                for (int tl = 0; tl < 2; ++tl) {
                    floatx4 zz = {};
                    floatx4 s1 = __builtin_amdgcn_mfma_f32_16x16x32_bf16(ak1, bq[tl], zz, 0, 0, 0);
                    floatx4 s2 = __builtin_amdgcn_mfma_f32_16x16x32_bf16(ak2, bq[tl], zz, 0, 0, 0);
                    floatx4 s3 = __builtin_amdgcn_mfma_f32_16x16x32_bf16(ak3, bq[tl], zz, 0, 0, 0);
                    floatx4 s4 = __builtin_amdgcn_mfma_f32_16x16x32_bf16(ak4, bq[tl], zz, 0, 0, 0);
                    us* pb = &Pb[w][tl][0];
                    uint2 p;
                    p.x = pk2t(fexp2(s1[1]), fexp2(s1[0]));
                    p.y = pk2t(fexp2(s1[3]), fexp2(s1[2]));
                    *(uint2*)(pb + sb) = p;
                    p.x = pk2t(fexp2(s2[1]), fexp2(s2[0]));
                    p.y = pk2t(fexp2(s2[3]), fexp2(s2[2]));
                    *(uint2*)(pb + sb + 256) = p;
                    p.x = pk2t(fexp2(s3[1]), fexp2(s3[0]));
                    p.y = pk2t(fexp2(s3[3]), fexp2(s3[2]));
                    *(uint2*)(pb + sb + 512) = p;
                    p.x = pk2t(fexp2(s4[1]), fexp2(s4[0]));
                    p.y = pk2t(fexp2(s4[3]), fexp2(s4[2]));
                    *(uint2*)(pb + sb + 768) = p;
                }

                asm volatile("s_waitcnt lgkmcnt(0)" ::: "memory");

#pragma unroll
                for (int tl = 0; tl < 2; ++tl) {
                    const us* pr = &Pb[w][tl][0] + l * 8;
                    short8 pf1 = *(const short8*)(pr);
                    short8 pf2 = *(const short8*)(pr + 512);
                    o1[tl] = __builtin_amdgcn_mfma_f32_16x16x32_bf16(a11, pf1, o1[tl], 0, 0, 0);
                    o2[tl] = __builtin_amdgcn_mfma_f32_16x16x32_bf16(a21, pf1, o2[tl], 0, 0, 0);
                    o3[tl] = __builtin_amdgcn_mfma_f32_16x16x32_bf16(ones, pf1, o3[tl], 0, 0, 0);
                    o1[tl] = __builtin_amdgcn_mfma_f32_16x16x32_bf16(a12, pf2, o1[tl], 0, 0, 0);
                    o2[tl] = __builtin_amdgcn_mfma_f32_16x16x32_bf16(a22, pf2, o2[tl], 0, 0, 0);
                    o3[tl] = __builtin_amdgcn_mfma_f32_16x16x32_bf16(ones, pf2, o3[tl], 0, 0, 0);
                }
                ak1 = nk1; ak2 = nk2; ak3 = nk3; ak4 = nk4;
            }

            us* np = ks ? num1 : num0;
#pragma unroll
            for (int tl = 0; tl < 2; ++tl) {
                const int q = q0 + tl * 16 + l15;
                us* op = np + ((size_t)z * N_DIM + q) * 256 + h * 32;
                uint2 lo, hi;
                lo.x = pk2(o1[tl][1], o1[tl][0]);
                lo.y = pk2(o1[tl][3], o1[tl][2]);
                hi.x = pk2(o2[tl][1], o2[tl][0]);
                hi.y = pk2(o2[tl][3], o2[tl][2]);
                *(uint2*)(op + quad * 4)      = lo;
                *(uint2*)(op + 16 + quad * 4) = hi;
                if (quad == 0) den[((size_t)ks * 16 + bh) * N_DIM + q] = o3[tl][0];
            }
        }
    }
    gbar(cnt, 4 * NB);

    // ================= phase 4: fused reduce + output GEMM (512 jobs) ========
    {
        int z = b >> 8, my = (b >> 6) & 3, nx = b & 63;
        int n0 = nx * 64, m0 = my * 64;
        const int wm = m0 + (w >> 1) * 32, wn = n0 + (w & 1) * 32;
        const us* Ap = Wb + 196608 + (size_t)(wm + l15) * 256 + quad * 8;
        const us* B0 = num0 + ((size_t)z * N_DIM + wn + l15) * 256 + quad * 8;
        const us* B1 = num1 + ((size_t)z * N_DIM + wn + l15) * 256 + quad * 8;
        const int qa = wn + l15, qb = wn + 16 + l15;

        floatx4 acc[2][2] = {};
#pragma unroll
        for (int k0 = 0; k0 < 256; k0 += 32) {
            const int bhh = z * 8 + (k0 >> 5);
            float inva = 1.f / (den[(size_t)bhh * N_DIM + qa] +
                                den[(size_t)(16 + bhh) * N_DIM + qa]);
            float invb = 1.f / (den[(size_t)bhh * N_DIM + qb] +
                                den[(size_t)(16 + bhh) * N_DIM + qb]);
            short8 a0 = *(const short8*)(Ap + k0);
            short8 a1 = *(const short8*)(Ap + k0 + 16 * 256);
            short8 r0a = *(const short8*)(B0 + k0);
            short8 r0b = *(const short8*)(B1 + k0);
            short8 r1a = *(const short8*)(B0 + k0 + 16 * 256);
            short8 r1b = *(const short8*)(B1 + k0 + 16 * 256);
            short8 b0, b1;
#pragma unroll
            for (int i = 0; i < 8; ++i) {
                b0[i] = (short)f2b((b2f((us)r0a[i]) + b2f((us)r0b[i])) * inva);
                b1[i] = (short)f2b((b2f((us)r1a[i]) + b2f((us)r1b[i])) * invb);
            }
            acc[0][0] = __builtin_amdgcn_mfma_f32_16x16x32_bf16(a0, b0, acc[0][0], 0, 0, 0);
            acc[0][1] = __builtin_amdgcn_mfma_f32_16x16x32_bf16(a0, b1, acc[0][1], 0, 0, 0);
            acc[1][0] = __builtin_amdgcn_mfma_f32_16x16x32_bf16(a1, b0, acc[1][0], 0, 0, 0);
            acc[1][1] = __builtin_amdgcn_mfma_f32_16x16x32_bf16(a1, b1, acc[1][1], 0, 0, 0);
        }

#pragma unroll
        for (int mt = 0; mt < 2; ++mt)
#pragma unroll
            for (int nt = 0; nt < 2; ++nt)
#pragma unroll
                for (int rr = 0; rr < 4; ++rr) {
                    int row = wm + mt * 16 + quad * 4 + rr;
                    int col = wn + nt * 16 + l15;
                    size_t oidx = ((size_t)z * 256 + row) * N_DIM + col;
                    Out[oidx] = acc[mt][nt][rr] + bst[768 + row] + x[oidx];
                }
    }
}

// ============================================= launch
extern "C" void kernel_launch(void* const* d_in, const int* in_sizes, int n_in,
                              void* d_out, int out_size, void* d_ws, size_t ws_size,
                              hipStream_t stream) {
    (void)in_sizes; (void)n_in; (void)out_size; (void)ws_size;
    const float* x     = (const float*)d_in[0];
    const float* gamma = (const float*)d_in[1];
    const float* beta  = (const float*)d_in[2];
    const float* Wq = (const float*)d_in[3]; const float* bq = (const float*)d_in[4];
    const float* Wk = (const float*)d_in[5]; const float* bk = (const float*)d_in[6];
    const float* Wv = (const float*)d_in[7]; const float* bv = (const float*)d_in[8];
    const float* Wo = (const float*)d_in[9]; const float* bo = (const float*)d_in[10];

    float* part = (float*)d_ws;                                  // 8 KB
    uns*   cnt  = (uns*)((char*)d_ws + 12288);                   // 128 B
    us*    Wb   = (us*)((char*)d_ws + 16384);                    // 512 KB
    float* bst  = (float*)((char*)d_ws + 16384 + 524288);        // 4 KB
    us*    XT   = (us*)((char*)d_ws + 16384 + 524288 + 4096);    // 4 MB (num0 later)
    us*    QT   = XT + 2 * CN;                                   // 4 MB
    us*    num1 = QT + 2 * CN;                                   // 4 MB
    float* den  = (float*)(num1 + 2 * CN);                       // 512 KB
    us*    Vb   = (us*)d_out;                                    // d_out front 4 MB
    us*    KTg  = (us*)d_out + 2 * CN;                           // d_out back 4 MB

    hipMemsetAsync(cnt, 0, 128, stream);
    k_mega<<<dim3(NB), dim3(256), 0, stream>>>(
        x, gamma, beta, Wq, Wk, Wv, Wo, bq, bk, bv, bo,
        part, Wb, bst, XT, QT, num1, den, Vb, KTg, (float*)d_out, cnt);
}